// Round 1
// baseline (108.340 us; speedup 1.0000x reference)
//
#include <hip/hip_runtime.h>
#include <hip/hip_bf16.h>

#define NTHREADS 256
#define EPSF 1e-5f

__device__ __forceinline__ void two_qubit(float xa, float xb, float pa, float pb,
                                          float cg, float sg, float ch, float sh,
                                          float& z0, float& z1) {
    const float ha = 0.5f * (xa + pa);
    const float hb = 0.5f * (xb + pb);
    float sa, ca, sb, cb;
    __sincosf(ha, &sa, &ca);
    __sincosf(hb, &sb, &cb);
    // product state, then CNOT(0,1) swaps |10> <-> |11>
    const float p00 = ca * cb, p01 = ca * sb;
    const float p10 = sa * sb, p11 = sa * cb;  // post-swap
    // Ry(ga) on qubit 0
    const float q00 = cg * p00 - sg * p10;
    const float q10 = sg * p00 + cg * p10;
    const float q01 = cg * p01 - sg * p11;
    const float q11 = sg * p01 + cg * p11;
    // Ry(gb) on qubit 1
    const float r00 = ch * q00 - sh * q01;
    const float r01 = sh * q00 + ch * q01;
    const float r10 = ch * q10 - sh * q11;
    const float r11 = sh * q10 + ch * q11;
    const float a = r00 * r00, b = r01 * r01, c = r10 * r10, d = r11 * r11;
    z0 = a + b - c - d;
    z1 = a - b + c - d;
}

__global__ __launch_bounds__(NTHREADS)
void quanv_fused(const float* __restrict__ x,
                 const float* __restrict__ qparams,
                 const float* __restrict__ in_w,
                 const float* __restrict__ in_b,
                 const float* __restrict__ out_w,
                 const float* __restrict__ out_b,
                 const float* __restrict__ lnw,
                 const float* __restrict__ lnb,
                 const float* __restrict__ lin_w,
                 const float* __restrict__ lin_b,
                 float* __restrict__ out)
{
    __shared__ float img[784];
    __shared__ float qs[196 * 5];   // stride 5: bank-conflict-free row writes
    __shared__ float ks[196 * 5];
    __shared__ float vs[196 * 5];
    __shared__ float ob[196 * 5];
    __shared__ float flat[784];     // LN output, already in (e,l) layout
    __shared__ float w_in[48], b_in[12], w_out[16], b_out[4];
    __shared__ float s_lnw[4], s_lnb[4], s_linb[10];
    __shared__ float qc[8];         // cos/sin of qparams[4..7]/2
    __shared__ float qp[4];         // qparams[0..3]
    __shared__ float wsum[4][10];
    __shared__ float logits_s[10];
    __shared__ float lse_s;

    const int tid = threadIdx.x;
    const int bid = blockIdx.x;

    // ---- stage image + weights into LDS ----
    const float* xb = x + (size_t)bid * 784;
    for (int i = tid; i < 784; i += NTHREADS) img[i] = xb[i];
    if (tid < 48) w_in[tid] = in_w[tid];
    {
        int t = tid - 64;  if (t >= 0 && t < 12) b_in[t] = in_b[t];
        t = tid - 80;      if (t >= 0 && t < 16) w_out[t] = out_w[t];
        t = tid - 96;      if (t >= 0 && t < 4)  b_out[t] = out_b[t];
        t = tid - 112;     if (t >= 0 && t < 4)  s_lnw[t] = lnw[t];
        t = tid - 128;     if (t >= 0 && t < 4)  s_lnb[t] = lnb[t];
        t = tid - 144;     if (t >= 0 && t < 10) s_linb[t] = lin_b[t];
        t = tid - 160;     if (t >= 0 && t < 4)  qp[t] = qparams[t];
        t = tid - 176;
        if (t >= 0 && t < 4) {
            const float g = 0.5f * qparams[4 + t];
            float sg, cg;
            __sincosf(g, &sg, &cg);
            qc[2 * t] = cg;
            qc[2 * t + 1] = sg;
        }
    }
    __syncthreads();

    // ---- quantum features + QKV projection (thread per patch) ----
    if (tid < 196) {
        const int l = tid;
        const int r = l / 14, c = l % 14;
        const float p0 = img[(2 * r) * 28 + 2 * c];
        const float p1 = img[(2 * r) * 28 + 2 * c + 1];
        const float p2 = img[(2 * r + 1) * 28 + 2 * c];
        const float p3 = img[(2 * r + 1) * 28 + 2 * c + 1];
        float z0, z1, z2, z3;
        two_qubit(p0, p1, qp[0], qp[1], qc[0], qc[1], qc[2], qc[3], z0, z1);
        two_qubit(p2, p3, qp[2], qp[3], qc[4], qc[5], qc[6], qc[7], z2, z3);
        #pragma unroll
        for (int j = 0; j < 12; ++j) {
            const float a = b_in[j] + z0 * w_in[j * 4] + z1 * w_in[j * 4 + 1]
                          + z2 * w_in[j * 4 + 2] + z3 * w_in[j * 4 + 3];
            if (j < 4)       qs[l * 5 + j] = a;
            else if (j < 8)  ks[l * 5 + (j - 4)] = a;
            else             vs[l * 5 + (j - 8)] = a;
        }
    }
    __syncthreads();

    // ---- attention: thread per (head, row); m-loop wave-uniform ----
    for (int w = tid; w < 392; w += NTHREADS) {
        const int l = w % 196;
        const int h = w / 196;
        const float q0 = qs[l * 5 + 2 * h];
        const float q1 = qs[l * 5 + 2 * h + 1];
        float mx = -1e30f;
        for (int m = 0; m < 196; ++m) {
            const float s = fmaf(q0, ks[m * 5 + 2 * h], q1 * ks[m * 5 + 2 * h + 1])
                            * 0.70710678118654752f;
            mx = fmaxf(mx, s);
        }
        float sum = 0.f, a0 = 0.f, a1 = 0.f;
        for (int m = 0; m < 196; ++m) {
            const float s = fmaf(q0, ks[m * 5 + 2 * h], q1 * ks[m * 5 + 2 * h + 1])
                            * 0.70710678118654752f;
            const float e = __expf(s - mx);
            sum += e;
            a0 = fmaf(e, vs[m * 5 + 2 * h], a0);
            a1 = fmaf(e, vs[m * 5 + 2 * h + 1], a1);
        }
        const float inv = 1.0f / sum;
        ob[l * 5 + 2 * h]     = a0 * inv;
        ob[l * 5 + 2 * h + 1] = a1 * inv;
    }
    __syncthreads();

    // ---- out-proj + LayerNorm (thread per row), write transposed layout ----
    if (tid < 196) {
        const int l = tid;
        const float f0 = ob[l * 5], f1 = ob[l * 5 + 1];
        const float f2 = ob[l * 5 + 2], f3 = ob[l * 5 + 3];
        const float e0 = b_out[0] + f0 * w_out[0]  + f1 * w_out[1]  + f2 * w_out[2]  + f3 * w_out[3];
        const float e1 = b_out[1] + f0 * w_out[4]  + f1 * w_out[5]  + f2 * w_out[6]  + f3 * w_out[7];
        const float e2 = b_out[2] + f0 * w_out[8]  + f1 * w_out[9]  + f2 * w_out[10] + f3 * w_out[11];
        const float e3 = b_out[3] + f0 * w_out[12] + f1 * w_out[13] + f2 * w_out[14] + f3 * w_out[15];
        const float mu = 0.25f * (e0 + e1 + e2 + e3);
        const float d0 = e0 - mu, d1 = e1 - mu, d2 = e2 - mu, d3 = e3 - mu;
        const float var = 0.25f * (d0 * d0 + d1 * d1 + d2 * d2 + d3 * d3);
        const float rs = rsqrtf(var + EPSF);
        flat[0 * 196 + l] = d0 * rs * s_lnw[0] + s_lnb[0];
        flat[1 * 196 + l] = d1 * rs * s_lnw[1] + s_lnb[1];
        flat[2 * 196 + l] = d2 * rs * s_lnw[2] + s_lnb[2];
        flat[3 * 196 + l] = d3 * rs * s_lnw[3] + s_lnb[3];
    }
    __syncthreads();

    // ---- final linear (10 x 784) + log_softmax ----
    float part[10];
    #pragma unroll
    for (int j = 0; j < 10; ++j) part[j] = 0.f;
    for (int i = tid; i < 784; i += NTHREADS) {
        const float v = flat[i];
        #pragma unroll
        for (int j = 0; j < 10; ++j)
            part[j] = fmaf(v, lin_w[j * 784 + i], part[j]);
    }
    const int lane = tid & 63, wv = tid >> 6;
    #pragma unroll
    for (int j = 0; j < 10; ++j) {
        float v = part[j];
        #pragma unroll
        for (int off = 32; off > 0; off >>= 1) v += __shfl_down(v, off);
        if (lane == 0) wsum[wv][j] = v;
    }
    __syncthreads();
    if (tid < 10)
        logits_s[tid] = wsum[0][tid] + wsum[1][tid] + wsum[2][tid] + wsum[3][tid] + s_linb[tid];
    __syncthreads();
    if (tid == 0) {
        float mx = logits_s[0];
        #pragma unroll
        for (int j = 1; j < 10; ++j) mx = fmaxf(mx, logits_s[j]);
        float se = 0.f;
        #pragma unroll
        for (int j = 0; j < 10; ++j) se += __expf(logits_s[j] - mx);
        lse_s = mx + __logf(se);
    }
    __syncthreads();
    if (tid < 10) out[(size_t)bid * 10 + tid] = logits_s[tid] - lse_s;
}

extern "C" void kernel_launch(void* const* d_in, const int* in_sizes, int n_in,
                              void* d_out, int out_size, void* d_ws, size_t ws_size,
                              hipStream_t stream) {
    const float* x        = (const float*)d_in[0];
    const float* qparams  = (const float*)d_in[1];
    const float* in_w     = (const float*)d_in[2];
    const float* in_b     = (const float*)d_in[3];
    const float* out_w    = (const float*)d_in[4];
    const float* out_b    = (const float*)d_in[5];
    const float* lnw      = (const float*)d_in[6];
    const float* lnb      = (const float*)d_in[7];
    const float* lin_w    = (const float*)d_in[8];
    const float* lin_b    = (const float*)d_in[9];
    float* out            = (float*)d_out;

    const int B = in_sizes[0] / 784;
    hipLaunchKernelGGL(quanv_fused, dim3(B), dim3(NTHREADS), 0, stream,
                       x, qparams, in_w, in_b, out_w, out_b, lnw, lnb, lin_w, lin_b, out);
}

// Round 2
// 49.142 us; speedup vs baseline: 2.2047x; 2.2047x over previous
//
#include <hip/hip_runtime.h>
#include <hip/hip_bf16.h>

#define NTHREADS 256
#define EPSF 1e-5f
#define INV_SQRT2 0.70710678118654752f

__device__ __forceinline__ void two_qubit(float xa, float xb, float pa, float pb,
                                          float cg, float sg, float ch, float sh,
                                          float& z0, float& z1) {
    const float ha = 0.5f * (xa + pa);
    const float hb = 0.5f * (xb + pb);
    float sa, ca, sb, cb;
    __sincosf(ha, &sa, &ca);
    __sincosf(hb, &sb, &cb);
    // product state, then CNOT(0,1) swaps |10> <-> |11>
    const float p00 = ca * cb, p01 = ca * sb;
    const float p10 = sa * sb, p11 = sa * cb;  // post-swap
    const float q00 = cg * p00 - sg * p10;
    const float q10 = sg * p00 + cg * p10;
    const float q01 = cg * p01 - sg * p11;
    const float q11 = sg * p01 + cg * p11;
    const float r00 = ch * q00 - sh * q01;
    const float r01 = sh * q00 + ch * q01;
    const float r10 = ch * q10 - sh * q11;
    const float r11 = sh * q10 + ch * q11;
    const float a = r00 * r00, b = r01 * r01, c = r10 * r10, d = r11 * r11;
    z0 = a + b - c - d;
    z1 = a - b + c - d;
}

__global__ __launch_bounds__(NTHREADS)
void quanv_fused(const float* __restrict__ x,
                 const float* __restrict__ qparams,
                 const float* __restrict__ in_w,
                 const float* __restrict__ in_b,
                 const float* __restrict__ out_w,
                 const float* __restrict__ out_b,
                 const float* __restrict__ lnw,
                 const float* __restrict__ lnb,
                 const float* __restrict__ lin_w,
                 const float* __restrict__ lin_b,
                 float* __restrict__ out)
{
    // img (staging+QKV) and flat (LN output) have disjoint live ranges -> overlay
    __shared__ __align__(16) float img_flat[784];
    __shared__ float qs[196 * 5];       // q, pre-scaled by 1/sqrt(2); stride 5
    __shared__ float4 kvs[392];         // [m*2+h] = {k0,k1,v0,v1} for head h
    __shared__ float ob[196 * 5];       // attention output, stride 5
    __shared__ float w_in[48], b_in[12], w_out[16], b_out[4];
    __shared__ float s_lnw[4], s_lnb[4], s_linb[10];
    __shared__ float qc[8];             // cos/sin of qparams[4..7]/2
    __shared__ float qp[4];             // qparams[0..3]
    __shared__ float wsum[4][10];
    __shared__ float logits_s[10];
    __shared__ float lse_s;

    const int tid = threadIdx.x;
    const int bid = blockIdx.x;

    // ---- stage image (float4) + weights into LDS ----
    const float4* xb4 = (const float4*)(x + (size_t)bid * 784);
    if (tid < 196) ((float4*)img_flat)[tid] = xb4[tid];
    if (tid < 48) w_in[tid] = in_w[tid];
    {
        int t = tid - 64;  if (t >= 0 && t < 12) b_in[t] = in_b[t];
        t = tid - 80;      if (t >= 0 && t < 16) w_out[t] = out_w[t];
        t = tid - 96;      if (t >= 0 && t < 4)  b_out[t] = out_b[t];
        t = tid - 112;     if (t >= 0 && t < 4)  s_lnw[t] = lnw[t];
        t = tid - 128;     if (t >= 0 && t < 4)  s_lnb[t] = lnb[t];
        t = tid - 144;     if (t >= 0 && t < 10) s_linb[t] = lin_b[t];
        t = tid - 160;     if (t >= 0 && t < 4)  qp[t] = qparams[t];
        t = tid - 176;
        if (t >= 0 && t < 4) {
            const float g = 0.5f * qparams[4 + t];
            float sg, cg;
            __sincosf(g, &sg, &cg);
            qc[2 * t] = cg;
            qc[2 * t + 1] = sg;
        }
    }
    __syncthreads();

    // ---- quantum features + QKV projection (thread per patch) ----
    if (tid < 196) {
        const int l = tid;
        const int r = l / 14, c = l % 14;
        const float p0 = img_flat[(2 * r) * 28 + 2 * c];
        const float p1 = img_flat[(2 * r) * 28 + 2 * c + 1];
        const float p2 = img_flat[(2 * r + 1) * 28 + 2 * c];
        const float p3 = img_flat[(2 * r + 1) * 28 + 2 * c + 1];
        float z0, z1, z2, z3;
        two_qubit(p0, p1, qp[0], qp[1], qc[0], qc[1], qc[2], qc[3], z0, z1);
        two_qubit(p2, p3, qp[2], qp[3], qc[4], qc[5], qc[6], qc[7], z2, z3);
        float a[12];
        #pragma unroll
        for (int j = 0; j < 12; ++j)
            a[j] = b_in[j] + z0 * w_in[j * 4] + z1 * w_in[j * 4 + 1]
                 + z2 * w_in[j * 4 + 2] + z3 * w_in[j * 4 + 3];
        qs[l * 5 + 0] = a[0] * INV_SQRT2;
        qs[l * 5 + 1] = a[1] * INV_SQRT2;
        qs[l * 5 + 2] = a[2] * INV_SQRT2;
        qs[l * 5 + 3] = a[3] * INV_SQRT2;
        kvs[2 * l]     = make_float4(a[4], a[5], a[8],  a[9]);   // head 0
        kvs[2 * l + 1] = make_float4(a[6], a[7], a[10], a[11]);  // head 1
    }
    __syncthreads();

    // ---- attention: single pass (scores bounded -> no max subtraction);
    //      2 lanes per (h,l) row, each does 98 m-iters; shfl_xor combine ----
    for (int id = tid; id < 784; id += NTHREADS) {
        const int rowid = id >> 1;      // 0..391
        const int half  = id & 1;
        const int l = rowid % 196;
        const int h = rowid / 196;
        const float q0 = qs[l * 5 + 2 * h];
        const float q1 = qs[l * 5 + 2 * h + 1];
        float sum = 0.f, a0 = 0.f, a1 = 0.f;
        const int m0 = half * 98;
        #pragma unroll 2
        for (int m = m0; m < m0 + 98; ++m) {
            const float4 kv = kvs[2 * m + h];   // broadcast ds_read_b128
            const float s = fmaf(q0, kv.x, q1 * kv.y);
            const float e = __expf(s);
            sum += e;
            a0 = fmaf(e, kv.z, a0);
            a1 = fmaf(e, kv.w, a1);
        }
        sum += __shfl_xor(sum, 1);
        a0  += __shfl_xor(a0, 1);
        a1  += __shfl_xor(a1, 1);
        const float inv = 1.0f / sum;
        if (half == 0) ob[l * 5 + 2 * h]     = a0 * inv;
        else           ob[l * 5 + 2 * h + 1] = a1 * inv;
    }
    __syncthreads();

    // ---- out-proj + LayerNorm (thread per row), write transposed layout ----
    if (tid < 196) {
        const int l = tid;
        const float f0 = ob[l * 5], f1 = ob[l * 5 + 1];
        const float f2 = ob[l * 5 + 2], f3 = ob[l * 5 + 3];
        const float e0 = b_out[0] + f0 * w_out[0]  + f1 * w_out[1]  + f2 * w_out[2]  + f3 * w_out[3];
        const float e1 = b_out[1] + f0 * w_out[4]  + f1 * w_out[5]  + f2 * w_out[6]  + f3 * w_out[7];
        const float e2 = b_out[2] + f0 * w_out[8]  + f1 * w_out[9]  + f2 * w_out[10] + f3 * w_out[11];
        const float e3 = b_out[3] + f0 * w_out[12] + f1 * w_out[13] + f2 * w_out[14] + f3 * w_out[15];
        const float mu = 0.25f * (e0 + e1 + e2 + e3);
        const float d0 = e0 - mu, d1 = e1 - mu, d2 = e2 - mu, d3 = e3 - mu;
        const float var = 0.25f * (d0 * d0 + d1 * d1 + d2 * d2 + d3 * d3);
        const float rs = rsqrtf(var + EPSF);
        img_flat[0 * 196 + l] = d0 * rs * s_lnw[0] + s_lnb[0];
        img_flat[1 * 196 + l] = d1 * rs * s_lnw[1] + s_lnb[1];
        img_flat[2 * 196 + l] = d2 * rs * s_lnw[2] + s_lnb[2];
        img_flat[3 * 196 + l] = d3 * rs * s_lnw[3] + s_lnb[3];
    }
    __syncthreads();

    // ---- final linear (10 x 784), float4 per thread + log_softmax ----
    float part[10];
    #pragma unroll
    for (int j = 0; j < 10; ++j) part[j] = 0.f;
    if (tid < 196) {
        const float4 f = ((const float4*)img_flat)[tid];
        const float4* lw = (const float4*)lin_w + tid;
        #pragma unroll
        for (int j = 0; j < 10; ++j) {
            const float4 w = lw[j * 196];
            part[j] = f.x * w.x + f.y * w.y + f.z * w.z + f.w * w.w;
        }
    }
    const int lane = tid & 63, wv = tid >> 6;
    #pragma unroll
    for (int j = 0; j < 10; ++j) {
        float v = part[j];
        #pragma unroll
        for (int off = 32; off > 0; off >>= 1) v += __shfl_down(v, off);
        if (lane == 0) wsum[wv][j] = v;
    }
    __syncthreads();
    if (tid < 10)
        logits_s[tid] = wsum[0][tid] + wsum[1][tid] + wsum[2][tid] + wsum[3][tid] + s_linb[tid];
    __syncthreads();
    if (tid == 0) {
        float mx = logits_s[0];
        #pragma unroll
        for (int j = 1; j < 10; ++j) mx = fmaxf(mx, logits_s[j]);
        float se = 0.f;
        #pragma unroll
        for (int j = 0; j < 10; ++j) se += __expf(logits_s[j] - mx);
        lse_s = mx + __logf(se);
    }
    __syncthreads();
    if (tid < 10) out[(size_t)bid * 10 + tid] = logits_s[tid] - lse_s;
}

extern "C" void kernel_launch(void* const* d_in, const int* in_sizes, int n_in,
                              void* d_out, int out_size, void* d_ws, size_t ws_size,
                              hipStream_t stream) {
    const float* x        = (const float*)d_in[0];
    const float* qparams  = (const float*)d_in[1];
    const float* in_w     = (const float*)d_in[2];
    const float* in_b     = (const float*)d_in[3];
    const float* out_w    = (const float*)d_in[4];
    const float* out_b    = (const float*)d_in[5];
    const float* lnw      = (const float*)d_in[6];
    const float* lnb      = (const float*)d_in[7];
    const float* lin_w    = (const float*)d_in[8];
    const float* lin_b    = (const float*)d_in[9];
    float* out            = (float*)d_out;

    const int B = in_sizes[0] / 784;
    hipLaunchKernelGGL(quanv_fused, dim3(B), dim3(NTHREADS), 0, stream,
                       x, qparams, in_w, in_b, out_w, out_b, lnw, lnb, lin_w, lin_b, out);
}